// Round 1
// baseline (999.925 us; speedup 1.0000x reference)
//
#include <hip/hip_runtime.h>
#include <math.h>

#define N_ 100
#define G_ 100
#define E_ 128

typedef _Float16 half4 __attribute__((ext_vector_type(4)));
typedef _Float16 half8 __attribute__((ext_vector_type(8)));
typedef float f32x4 __attribute__((ext_vector_type(4)));

#define MFMA32(a,b,c) __builtin_amdgcn_mfma_f32_16x16x32_f16(a,b,c,0,0,0)
#define MFMA16(a,b,c) __builtin_amdgcn_mfma_f32_16x16x16f16(a,b,c,0,0,0)

// ---- prep: fp16 hi/lo split transposed weights into ws ----
// ws layout (fp16 elements): mat m in {0:Wsum(=Wqf+Wql),1:Wk,2:Wv,3:Wc}:
//   hi plane @ m*32768, lo plane @ m*32768+16384, each [o=128][i=128] (W^T)
extern "C" __global__ void prep_weights(const float* __restrict__ Wqf,
                                        const float* __restrict__ Wql,
                                        const float* __restrict__ Wk,
                                        const float* __restrict__ Wv,
                                        const float* __restrict__ Wc,
                                        _Float16* __restrict__ ws) {
    int t = blockIdx.x * 256 + threadIdx.x;      // 0..65535
    int m = t >> 14, r = t & 16383;
    int o = r & 127, i = r >> 7;
    float v;
    if      (m == 0) v = Wqf[i * 128 + o] + Wql[i * 128 + o];
    else if (m == 1) v = Wk [i * 128 + o];
    else if (m == 2) v = Wv [i * 128 + o];
    else             v = Wc [i * 128 + o];
    _Float16 h = (_Float16)v;
    _Float16 l = (_Float16)(v - (float)h);
    ws[m * 32768 + o * 128 + i]         = h;     // W^T[o][i] hi
    ws[m * 32768 + 16384 + o * 128 + i] = l;     // lo
}

// LDS element offsets (fp16 elements). total 72720 el = 145440 B
#define OFF_NH 0                    // nodes hi [112][136] (rows 100..111 zero)
#define OFF_NL 15232                // nodes lo
#define OFF_SCR 30464               // scratch region (31488 el):
#define OFF_LH  OFF_SCR             //   phase0-P1: last hi [112][136]
#define OFF_LL  (OFF_SCR + 15232)   //   last lo
#define OFF_KH  OFF_SCR             //   P2-P3: K hi [112][72] (cols h*16+d, d<16)
#define OFF_KL  (OFF_SCR + 8064)    //   K lo
#define OFF_VH  (OFF_SCR + 16128)   //   V^T hi [64][120] (row e_local, col n)
#define OFF_VL  (OFF_SCR + 23808)   //   V^T lo
                                    //   P5 out-stage: fp32 [100][113] @ OFF_SCR
#define OFF_MASK 61952              // mask fp16 [100][100]
#define OFF_SF  71952               // fp32: GRAPH[128] @0, QG[128] @128, BC[128] @256

extern "C" __global__ void __launch_bounds__(448, 2)
pomo_decoder(const float* __restrict__ nodes,   // [B,N,E]
             const float* __restrict__ last,    // [B,G,E]
             const float* __restrict__ mask,    // [B,G,N]
             const float* __restrict__ Wqg,     // [E,128] fp32
             const _Float16* __restrict__ ws,   // fp16 hi/lo transposed weights
             const float* __restrict__ bc,      // [128]
             float* __restrict__ out)           // [B,G,N]
{
    __shared__ _Float16 SB[72720];
    float* SF = (float*)(SB + OFF_SF);

    const int tid  = threadIdx.x;
    const int w    = tid >> 6;          // 0..6, wave w owns rows g = 16w..16w+15
    const int lane = tid & 63;
    const int lrow = lane & 15;
    const int lq   = lane >> 4;
    const int b    = blockIdx.x;

    const float* nb = nodes + (size_t)b * N_ * E_;
    const float* lb = last  + (size_t)b * G_ * E_;
    const float* mb = mask  + (size_t)b * G_ * N_;
    float*       ob = out   + (size_t)b * G_ * N_;

    const _Float16* WsH = ws;
    const _Float16* WsL = ws + 16384;
    const _Float16* WkH = ws + 32768;
    const _Float16* WkL = ws + 49152;
    const _Float16* WvH = ws + 65536;
    const _Float16* WvL = ws + 81920;
    const _Float16* WcH = ws + 98304;
    const _Float16* WcL = ws + 114688;

    // ---------- phase 0: stage nodes+last (fp16 hi/lo), mask, bc; zero pads ----------
    {
        const float4* nb4 = (const float4*)nb;
        const float4* lb4 = (const float4*)lb;
        for (int f = tid; f < 3200; f += 448) {
            const int row = f >> 5;
            const int c4  = (f & 31) << 2;
            float4 v = nb4[f];
            half4 h, l;
            h[0]=(_Float16)v.x; l[0]=(_Float16)(v.x-(float)h[0]);
            h[1]=(_Float16)v.y; l[1]=(_Float16)(v.y-(float)h[1]);
            h[2]=(_Float16)v.z; l[2]=(_Float16)(v.z-(float)h[2]);
            h[3]=(_Float16)v.w; l[3]=(_Float16)(v.w-(float)h[3]);
            *(half4*)&SB[OFF_NH + row*136 + c4] = h;
            *(half4*)&SB[OFF_NL + row*136 + c4] = l;
            v = lb4[f];
            h[0]=(_Float16)v.x; l[0]=(_Float16)(v.x-(float)h[0]);
            h[1]=(_Float16)v.y; l[1]=(_Float16)(v.y-(float)h[1]);
            h[2]=(_Float16)v.z; l[2]=(_Float16)(v.z-(float)h[2]);
            h[3]=(_Float16)v.w; l[3]=(_Float16)(v.w-(float)h[3]);
            *(half4*)&SB[OFF_LH + row*136 + c4] = h;
            *(half4*)&SB[OFF_LL + row*136 + c4] = l;
        }
        // zero pad rows 100..111 of nodes and last planes (finite garbage guard)
        for (int t2 = tid; t2 < 1632; t2 += 448) {
            const int e = 100*136 + t2;
            SB[OFF_NH + e] = (_Float16)0.f;
            SB[OFF_NL + e] = (_Float16)0.f;
            SB[OFF_LH + e] = (_Float16)0.f;
            SB[OFF_LL + e] = (_Float16)0.f;
        }
        for (int t2 = tid; t2 < 10000; t2 += 448)
            SB[OFF_MASK + t2] = (_Float16)mb[t2];
        if (tid < 128) SF[256 + tid] = bc[tid];
    }
    __syncthreads();

    // graph mean (per column, from hi+lo reconstruction)
    if (tid < 128) {
        float s = 0.f;
        for (int r = 0; r < 100; ++r)
            s += (float)SB[OFF_NH + r*136 + tid] + (float)SB[OFF_NL + r*136 + tid];
        SF[tid] = s * 0.01f;
    }
    __syncthreads();
    if (tid < 128) {                        // q_graph = graph @ Wq_graph (fp32)
        float a = 0.f;
        for (int e = 0; e < 128; ++e) a = fmaf(SF[e], Wqg[e * 128 + tid], a);
        SF[128 + tid] = a;
    }
    __syncthreads();

    // ---------- P1: q^T[e][g] = (Wsum^T · last^T) + qg, kept in registers ----------
    // lane holds q[g = 16w + (lane&15)][e = 16et + 4lq + r]  (hi/lo half4 per et)
    half4 qh[8], qlo[8];
    {
        f32x4 acc[8];
        #pragma unroll
        for (int et = 0; et < 8; ++et) { f32x4 z = {0.f,0.f,0.f,0.f}; acc[et] = z; }
        #pragma unroll
        for (int kk = 0; kk < 4; ++kk) {
            half8 bh = *(const half8*)&SB[OFF_LH + (w*16 + lrow)*136 + kk*32 + lq*8];
            half8 bl = *(const half8*)&SB[OFF_LL + (w*16 + lrow)*136 + kk*32 + lq*8];
            #pragma unroll
            for (int et = 0; et < 8; ++et) {
                const int wo = (et*16 + lrow)*128 + kk*32 + lq*8;
                half8 ah = *(const half8*)(WsH + wo);
                half8 al = *(const half8*)(WsL + wo);
                acc[et] = MFMA32(ah, bh, acc[et]);
                acc[et] = MFMA32(ah, bl, acc[et]);
                acc[et] = MFMA32(al, bh, acc[et]);
            }
        }
        #pragma unroll
        for (int et = 0; et < 8; ++et)
            #pragma unroll
            for (int r = 0; r < 4; ++r) {
                float qv = acc[et][r] + SF[128 + et*16 + lq*4 + r];
                qh[et][r]  = (_Float16)qv;
                qlo[et][r] = (_Float16)(qv - (float)qh[et][r]);
            }
    }
    __syncthreads();   // last region is dead; P2 overwrites it with K/V

    const int gmrow = (w*16 + lrow > 99) ? 99 : (w*16 + lrow);

    // ---------- attention: two halves of 4 heads ----------
    half4 oh[8], olo[8];   // O[g][16*hg + 4lq + r] hi/lo, hg = head
    #pragma unroll
    for (int hh = 0; hh < 2; ++hh) {
        // ---- P2: K[n][h*16+d] and V^T[e_local][n] projections for this half ----
        for (int i = 0; i < 8; ++i) {
            const int tau = w*8 + i;            // 0..55: 28 K-tiles then 28 V-tiles
            const bool isK = (tau < 28);
            const int tt = isK ? tau : tau - 28;
            const int nt = tt >> 2, et = tt & 3;
            f32x4 acc = {0.f,0.f,0.f,0.f};
            const _Float16* WH = isK ? WkH : WvH;
            const _Float16* WL = isK ? WkL : WvL;
            if (isK) {
                // D[n][e]: A = nodes (row n), B = W^T (col e)
                #pragma unroll
                for (int kk = 0; kk < 4; ++kk) {
                    half8 ah = *(const half8*)&SB[OFF_NH + (nt*16 + lrow)*136 + kk*32 + lq*8];
                    half8 al = *(const half8*)&SB[OFF_NL + (nt*16 + lrow)*136 + kk*32 + lq*8];
                    const int wo = (hh*64 + et*16 + lrow)*128 + kk*32 + lq*8;
                    half8 bh = *(const half8*)(WH + wo);
                    half8 bl = *(const half8*)(WL + wo);
                    acc = MFMA32(ah, bh, acc);
                    acc = MFMA32(ah, bl, acc);
                    acc = MFMA32(al, bh, acc);
                }
                #pragma unroll
                for (int r = 0; r < 4; ++r) {
                    const int n = nt*16 + lq*4 + r;
                    if (n < N_) {
                        float v = acc[r];
                        _Float16 h = (_Float16)v;
                        SB[OFF_KH + n*72 + et*16 + lrow] = h;
                        SB[OFF_KL + n*72 + et*16 + lrow] = (_Float16)(v - (float)h);
                    }
                }
            } else {
                // D[e][n]: A = W^T (row e), B = nodes (col n)
                #pragma unroll
                for (int kk = 0; kk < 4; ++kk) {
                    const int wo = (hh*64 + et*16 + lrow)*128 + kk*32 + lq*8;
                    half8 ah = *(const half8*)(WH + wo);
                    half8 al = *(const half8*)(WL + wo);
                    half8 bh = *(const half8*)&SB[OFF_NH + (nt*16 + lrow)*136 + kk*32 + lq*8];
                    half8 bl = *(const half8*)&SB[OFF_NL + (nt*16 + lrow)*136 + kk*32 + lq*8];
                    acc = MFMA32(ah, bh, acc);
                    acc = MFMA32(ah, bl, acc);
                    acc = MFMA32(al, bh, acc);
                }
                #pragma unroll
                for (int r = 0; r < 4; ++r) {
                    const int e = et*16 + lq*4 + r;     // e_local 0..63
                    const int n = nt*16 + lrow;         // 0..111
                    float v = (n < N_) ? acc[r] : 0.f;
                    _Float16 h = (_Float16)v;
                    SB[OFF_VH + e*120 + n] = h;
                    SB[OFF_VL + e*120 + n] = (_Float16)(v - (float)h);
                }
            }
        }
        __syncthreads();

        // ---- P3: per wave, 4 heads: S^T = K·q, softmax over n, O^T = V^T·P ----
        #pragma unroll
        for (int hl = 0; hl < 4; ++hl) {
            const int hg = hh*4 + hl;
            f32x4 sc[7];
            #pragma unroll
            for (int nt = 0; nt < 7; ++nt) {
                half4 kh = *(const half4*)&SB[OFF_KH + (nt*16 + lrow)*72 + hl*16 + lq*4];
                half4 kl = *(const half4*)&SB[OFF_KL + (nt*16 + lrow)*72 + hl*16 + lq*4];
                f32x4 z = {0.f,0.f,0.f,0.f};
                z = MFMA16(kh, qh[hg], z);
                z = MFMA16(kh, qlo[hg], z);
                z = MFMA16(kl, qh[hg], z);
                sc[nt] = z;   // S^T[n = 16nt+4lq+r][g = lane&15]
            }
            float mx = -INFINITY;
            #pragma unroll
            for (int nt = 0; nt < 7; ++nt)
                #pragma unroll
                for (int r = 0; r < 4; ++r) {
                    const int n = nt*16 + lq*4 + r;
                    float s = (n < N_)
                        ? sc[nt][r]*0.25f + (float)SB[OFF_MASK + gmrow*100 + n]
                        : -INFINITY;
                    sc[nt][r] = s;
                    mx = fmaxf(mx, s);
                }
            mx = fmaxf(mx, __shfl_xor(mx, 16));
            mx = fmaxf(mx, __shfl_xor(mx, 32));
            float sum = 0.f;
            half4 ph[7], pl[7];
            #pragma unroll
            for (int nt = 0; nt < 7; ++nt)
                #pragma unroll
                for (int r = 0; r < 4; ++r) {
                    float p = __expf(sc[nt][r] - mx);
                    sum += p;
                    ph[nt][r] = (_Float16)p;
                    pl[nt][r] = (_Float16)(p - (float)ph[nt][r]);
                }
            sum += __shfl_xor(sum, 16);
            sum += __shfl_xor(sum, 32);
            const float inv = 1.f / sum;
            f32x4 oacc = {0.f,0.f,0.f,0.f};
            #pragma unroll
            for (int nt = 0; nt < 7; ++nt) {
                half4 vh = *(const half4*)&SB[OFF_VH + (hl*16 + lrow)*120 + nt*16 + lq*4];
                half4 vl = *(const half4*)&SB[OFF_VL + (hl*16 + lrow)*120 + nt*16 + lq*4];
                oacc = MFMA16(vh, ph[nt], oacc);
                oacc = MFMA16(vh, pl[nt], oacc);
                oacc = MFMA16(vl, ph[nt], oacc);
            }
            #pragma unroll
            for (int r = 0; r < 4; ++r) {
                float v = oacc[r] * inv;     // O[g][16hg + 4lq + r]
                oh[hg][r]  = (_Float16)v;
                olo[hg][r] = (_Float16)(v - (float)oh[hg][r]);
            }
        }
        __syncthreads();   // before next half's P2 overwrites K/V
    }

    // ---------- P4: mh^T[e][g] = Wc^T · O^T + bc, kept in registers ----------
    half4 mhh[8], mhl[8];
    #pragma unroll
    for (int et = 0; et < 8; ++et) {
        f32x4 acc = {0.f,0.f,0.f,0.f};
        #pragma unroll
        for (int kc = 0; kc < 8; ++kc) {
            const int wo = (et*16 + lrow)*128 + kc*16 + lq*4;
            half4 ah = *(const half4*)(WcH + wo);
            half4 al = *(const half4*)(WcL + wo);
            acc = MFMA16(ah, oh[kc], acc);
            acc = MFMA16(ah, olo[kc], acc);
            acc = MFMA16(al, oh[kc], acc);
        }
        #pragma unroll
        for (int r = 0; r < 4; ++r) {
            float v = acc[r] + SF[256 + et*16 + lq*4 + r];
            mhh[et][r] = (_Float16)v;
            mhl[et][r] = (_Float16)(v - (float)mhh[et][r]);
        }
    }

    // ---------- P5: S2^T[n][g] = nodes · mh^T, tanh clip, softmax, store ----------
    f32x4 s2[7];
    #pragma unroll
    for (int nt = 0; nt < 7; ++nt) {
        f32x4 acc = {0.f,0.f,0.f,0.f};
        #pragma unroll
        for (int kc = 0; kc < 8; ++kc) {
            half4 ah = *(const half4*)&SB[OFF_NH + (nt*16 + lrow)*136 + kc*16 + lq*4];
            half4 al = *(const half4*)&SB[OFF_NL + (nt*16 + lrow)*136 + kc*16 + lq*4];
            acc = MFMA16(ah, mhh[kc], acc);
            acc = MFMA16(ah, mhl[kc], acc);
            acc = MFMA16(al, mhh[kc], acc);
        }
        s2[nt] = acc;
    }
    {
        float mx = -INFINITY;
        #pragma unroll
        for (int nt = 0; nt < 7; ++nt)
            #pragma unroll
            for (int r = 0; r < 4; ++r) {
                const int n = nt*16 + lq*4 + r;
                float s;
                if (n < N_) {
                    float x = s2[nt][r] * 0.08838834764831845f;   // 1/sqrt(128)
                    x = fminf(fmaxf(x, -15.f), 15.f);
                    const float e2 = __expf(2.f * x);
                    const float th = 1.f - 2.f / (e2 + 1.f);
                    s = 10.f * th + (float)SB[OFF_MASK + gmrow*100 + n];
                } else s = -INFINITY;
                s2[nt][r] = s;
                mx = fmaxf(mx, s);
            }
        mx = fmaxf(mx, __shfl_xor(mx, 16));
        mx = fmaxf(mx, __shfl_xor(mx, 32));
        float sum = 0.f;
        #pragma unroll
        for (int nt = 0; nt < 7; ++nt)
            #pragma unroll
            for (int r = 0; r < 4; ++r) {
                float p = __expf(s2[nt][r] - mx);
                s2[nt][r] = p;
                sum += p;
            }
        sum += __shfl_xor(sum, 16);
        sum += __shfl_xor(sum, 32);
        const float inv = 1.f / sum;
        // stage transposed result into fp32 LDS [100][113] for coalesced writeout
        float* OUTF = (float*)(SB + OFF_SCR);
        const int g = w*16 + lrow;
        if (g < G_) {
            #pragma unroll
            for (int nt = 0; nt < 7; ++nt)
                #pragma unroll
                for (int r = 0; r < 4; ++r) {
                    const int n = nt*16 + lq*4 + r;
                    if (n < N_) OUTF[g*113 + n] = s2[nt][r] * inv;
                }
        }
    }
    __syncthreads();
    {
        const float* OUTF = (const float*)(SB + OFF_SCR);
        for (int t2 = tid; t2 < G_ * N_; t2 += 448) {
            const int g2 = t2 / 100;
            const int n2 = t2 - g2 * 100;
            ob[t2] = OUTF[g2*113 + n2];
        }
    }
}

extern "C" void kernel_launch(void* const* d_in, const int* in_sizes, int n_in,
                              void* d_out, int out_size, void* d_ws, size_t ws_size,
                              hipStream_t stream) {
    const float* nodes = (const float*)d_in[0];
    const float* last  = (const float*)d_in[1];
    const float* mask  = (const float*)d_in[2];
    const float* Wqg   = (const float*)d_in[3];
    const float* Wqf   = (const float*)d_in[4];
    const float* Wql   = (const float*)d_in[5];
    const float* Wk    = (const float*)d_in[6];
    const float* Wv    = (const float*)d_in[7];
    const float* Wc    = (const float*)d_in[8];
    const float* bc    = (const float*)d_in[9];
    float* out = (float*)d_out;
    _Float16* ws = (_Float16*)d_ws;              // needs 262144 B

    hipLaunchKernelGGL(prep_weights, dim3(256), dim3(256), 0, stream,
                       Wqf, Wql, Wk, Wv, Wc, ws);

    const int B = in_sizes[0] / (N_ * E_);       // 2048
    hipLaunchKernelGGL(pomo_decoder, dim3(B), dim3(448), 0, stream,
                       nodes, last, mask, Wqg, ws, bc, out);
}